// Round 1
// baseline (5597.325 us; speedup 1.0000x reference)
//
#include <hip/hip_runtime.h>
#include <stdint.h>

// Problem constants (from reference)
#define B_N 2048
#define T_N 100
#define H_N 256
#define L_N 128
#define NV_N 5
#define COLS (H_N + 2 * L_N)   // 512 columns of all_hidden_states

// Output element offsets, concatenated in return order:
// new_h [B,H], all_hidden_states [B,T,512], seg_rep [B,H]
static constexpr long long OUT_ALLH = (long long)B_N * H_N;                     // 524288
static constexpr long long OUT_SEG  = OUT_ALLH + (long long)B_N * T_N * COLS;   // 105381888

__device__ __forceinline__ float bits2f(uint32_t u) {
    union { uint32_t u; float f; } v; v.u = u; return v.f;
}
__device__ __forceinline__ uint16_t f2bf(float f) {
    union { float f; uint32_t u; } v; v.f = f;
    uint32_t r = (v.u + 0x7FFFu + ((v.u >> 16) & 1u)) >> 16;   // round-nearest-even
    return (uint16_t)r;
}

// ---------------------------------------------------------------------------
// Runtime dtype detection (unchanged from verified kernel): majority vote on
// the fp32-exponent field of 64 words of W_cs.
// ---------------------------------------------------------------------------
__device__ __forceinline__ int detect_f32(const uint32_t* __restrict__ w) {
    int cnt = 0;
    #pragma unroll 8
    for (int i = 0; i < 64; ++i) {
        uint32_t e = (w[i] >> 23) & 0xFFu;
        cnt += (e >= 97u && e <= 130u) ? 1 : 0;
    }
    return cnt >= 32 ? 1 : 0;
}

// ---------------------------------------------------------------------------
// Dtype-abstracted element access. Index units are ELEMENTS.
// ---------------------------------------------------------------------------
template <bool F32> struct IO;

template <> struct IO<true> {
    static __device__ __forceinline__ void ld4(const void* p, long long idx, float f[4]) {
        const float4 v = *(const float4*)((const float*)p + idx);
        f[0] = v.x; f[1] = v.y; f[2] = v.z; f[3] = v.w;
    }
    static __device__ __forceinline__ float ld1(const void* p, long long idx) {
        return ((const float*)p)[idx];
    }
    static __device__ __forceinline__ void st4(void* p, long long idx, const float f[4]) {
        *(float4*)((float*)p + idx) = make_float4(f[0], f[1], f[2], f[3]);
    }
    static __device__ __forceinline__ void st4z(void* p, long long idx) {
        *(float4*)((float*)p + idx) = make_float4(0.f, 0.f, 0.f, 0.f);
    }
};

template <> struct IO<false> {
    static __device__ __forceinline__ void ld4(const void* p, long long idx, float f[4]) {
        uint2 u = *(const uint2*)((const uint16_t*)p + idx);
        f[0] = bits2f(u.x << 16);
        f[1] = bits2f(u.x & 0xFFFF0000u);
        f[2] = bits2f(u.y << 16);
        f[3] = bits2f(u.y & 0xFFFF0000u);
    }
    static __device__ __forceinline__ float ld1(const void* p, long long idx) {
        return bits2f(((uint32_t)((const uint16_t*)p)[idx]) << 16);
    }
    static __device__ __forceinline__ void st4(void* p, long long idx, const float f[4]) {
        uint2 u;
        u.x = (uint32_t)f2bf(f[0]) | ((uint32_t)f2bf(f[1]) << 16);
        u.y = (uint32_t)f2bf(f[2]) | ((uint32_t)f2bf(f[3]) << 16);
        *(uint2*)((uint16_t*)p + idx) = u;
    }
    static __device__ __forceinline__ void st4z(void* p, long long idx) {
        *(uint2*)((uint16_t*)p + idx) = make_uint2(0u, 0u);
    }
};

__device__ __forceinline__ float sigmoid_f(float x) {
    x = fminf(fmaxf(x, -30.f), 30.f);
    return 1.f / (1.f + __expf(-x));
}
__device__ __forceinline__ float tanh_f(float x) {
    x = fminf(fmaxf(x, -15.f), 15.f);
    float e = __expf(-2.f * x);
    return (1.f - e) / (1.f + e);
}

// ---------------------------------------------------------------------------
// Kernel 1: fill all_hidden_states[:, :, 256:512] with masked tree/graph
// broadcast (zeros at t >= len). Unchanged from verified kernel.
// ---------------------------------------------------------------------------
template <bool F32>
__global__ __launch_bounds__(256) void latent_fill_kernel(
    const void* __restrict__ tree,
    const void* __restrict__ graph,
    const int* __restrict__ lengths,
    const void* __restrict__ Wcs_detect,
    void* __restrict__ out)
{
    __shared__ int s_is32;
    if (threadIdx.x == 0) s_is32 = detect_f32((const uint32_t*)Wcs_detect);
    __syncthreads();
    if ((s_is32 != 0) != F32) return;

    long long idx = (long long)blockIdx.x * 256 + threadIdx.x;   // 0 .. B*T*64
    int c = ((int)(idx & 63)) * 4;           // 0..252 within latent cols
    long long bt = idx >> 6;                 // b*T + t
    int t = (int)(bt % T_N);
    int b = (int)(bt / T_N);

    long long dst = OUT_ALLH + bt * COLS + H_N + c;
    if (t < lengths[b]) {
        float v[4];
        if (c < L_N) IO<F32>::ld4(tree, (long long)b * L_N + c, v);
        else         IO<F32>::ld4(graph, (long long)b * L_N + (c - L_N), v);
        IO<F32>::st4(out, dst, v);
    } else {
        IO<F32>::st4z(out, dst);
    }
}

// ---------------------------------------------------------------------------
// Kernel 2: column-split batched GRU.
//   block = 256 threads = 8 batch rows x 32 col-groups; thread owns 8 columns
//   of ONE row. Each weight element is loaded ONCE per block per step
//   (8x reuse vs the old 1-row-per-wave kernel -> L2 traffic 83 GB -> ~18 GB).
//   h lives in LDS as xh[row][k] = [x(5); h(256)], matching W's row layout;
//   per-k broadcast is one float4 LDS read per 4 k (conflict-free: row
//   stride 268 words, banks r*12+k distinct mod 32).
//   Rows are independent across waves except via their own h -> recurrence
//   closes in-block with 2 barriers/step:
//     [write x(t)+h(t)] bar1 [pass1 z,r; write xg] bar2 [pass2 h~; update]
// ---------------------------------------------------------------------------
template <bool F32>
__global__ __launch_bounds__(256, 1) void gru_kernel(
    const void* __restrict__ x_seq,
    const void* __restrict__ hidden,
    const void* __restrict__ graph,
    const int* __restrict__ lengths,
    const void* __restrict__ Wcs, const void* __restrict__ bcs,
    const void* __restrict__ Wz,  const void* __restrict__ bz,
    const void* __restrict__ Wr,  const void* __restrict__ br,
    const void* __restrict__ Wh,  const void* __restrict__ bh,
    void* __restrict__ out)
{
    __shared__ int s_is32;
    if (threadIdx.x == 0) s_is32 = detect_f32((const uint32_t*)Wcs);
    __syncthreads();
    if ((s_is32 != 0) != F32) return;

    constexpr int RB   = 8;     // batch rows per block
    constexpr int KXH  = NV_N + H_N;        // 261
    constexpr int XH_S = 268;   // row stride (words); 268%32=12 -> 8 rows hit
                                // distinct bank quads for b128 reads
    constexpr int KCS  = H_N + L_N;         // 384
    constexpr int CS_S = 388;   // 388%32=4 -> distinct banks across rows

    __shared__ float xh[RB][XH_S];   // [x(t)(5); h(256)] per row
    __shared__ float xg[RB][XH_S];   // [x(t)(5); r*h(256)] per row
    __shared__ float cs[RB][CS_S];   // [hidden(256); graph(128)] per row
    __shared__ int s_len[RB];

    const int tid = threadIdx.x;
    const int cg  = tid & 31;        // col-group 0..31
    const int row = tid >> 5;        // 0..7
    const int c0  = cg * 8;          // first of this thread's 8 columns

    if (tid < RB) {
        int L = lengths[blockIdx.x * RB + tid];
        s_len[tid] = min(max(L, 1), T_N);
    }
    __syncthreads();

    const int b   = blockIdx.x * RB + row;
    const int len = s_len[row];
    int maxlen = 1;
    #pragma unroll
    for (int i = 0; i < RB; ++i) maxlen = max(maxlen, s_len[i]);

    // ---- stage [hidden, graph] into cs (coalesced within rows) ----
    for (int i = tid; i < RB * KCS; i += 256) {
        int r = i / KCS;
        int k = i - r * KCS;
        int bb = blockIdx.x * RB + r;
        float v = (k < H_N) ? IO<F32>::ld1(hidden, (long long)bb * H_N + k)
                            : IO<F32>::ld1(graph,  (long long)bb * L_N + (k - H_N));
        cs[r][k] = v;
    }
    __syncthreads();

    // ---- h0 = relu(cs @ Wcs + bcs) for this thread's 8 columns ----
    float h[8];
    {
        float acc[8];
        IO<F32>::ld4(bcs, c0, acc);
        IO<F32>::ld4(bcs, c0 + 4, acc + 4);
        for (int k = 0; k < KCS; k += 4) {
            const float4 hv = *reinterpret_cast<const float4*>(&cs[row][k]);
            #pragma unroll
            for (int kk = 0; kk < 4; ++kk) {
                const float hvk = (&hv.x)[kk];
                float w[8];
                IO<F32>::ld4(Wcs, (long long)(k + kk) * H_N + c0,     w);
                IO<F32>::ld4(Wcs, (long long)(k + kk) * H_N + c0 + 4, w + 4);
                #pragma unroll
                for (int j = 0; j < 8; ++j) acc[j] += hvk * w[j];
            }
        }
        #pragma unroll
        for (int j = 0; j < 8; ++j) {
            h[j] = fmaxf(acc[j], 0.f);
            xh[row][NV_N + c0 + j] = h[j];
        }
    }

    // ---- biases (loop-invariant) ----
    float bzv[8], brv[8], bhv[8];
    IO<F32>::ld4(bz, c0, bzv); IO<F32>::ld4(bz, c0 + 4, bzv + 4);
    IO<F32>::ld4(br, c0, brv); IO<F32>::ld4(br, c0 + 4, brv + 4);
    IO<F32>::ld4(bh, c0, bhv); IO<F32>::ld4(bh, c0 + 4, bhv + 4);

    float smax[8];
    #pragma unroll
    for (int j = 0; j < 8; ++j) smax[j] = -1e30f;

    // ---- x prefetch (threads 0..39 own one (row, nuc) slot each) ----
    const int xr = tid / NV_N;
    const int xi = tid - xr * NV_N;
    float xv = 0.f;
    if (tid < RB * NV_N)
        xv = IO<F32>::ld1(x_seq, ((long long)(blockIdx.x * RB + xr) * T_N + 0) * NV_N + xi);

    for (int t = 0; t < maxlen; ++t) {
        if (tid < RB * NV_N) xh[xr][xi] = xv;   // x(t) -> xh (h(t) already there)
        __syncthreads();                        // bar1
        if (tid < RB * NV_N) {
            xg[xr][xi] = xv;                    // x(t) -> xg (safe: no xg readers here)
            int tn = (t + 1 < T_N) ? t + 1 : T_N - 1;
            xv = IO<F32>::ld1(x_seq, ((long long)(blockIdx.x * RB + xr) * T_N + tn) * NV_N + xi);
        }

        // ---- pass 1: z and r ----
        float az[8], ar[8];
        #pragma unroll
        for (int j = 0; j < 8; ++j) { az[j] = bzv[j]; ar[j] = brv[j]; }

        for (int k = 0; k < KXH - 1; k += 4) {   // 0..259
            const float4 hv = *reinterpret_cast<const float4*>(&xh[row][k]);
            #pragma unroll
            for (int kk = 0; kk < 4; ++kk) {
                const float hvk = (&hv.x)[kk];
                float wz[8], wr[8];
                IO<F32>::ld4(Wz, (long long)(k + kk) * H_N + c0,     wz);
                IO<F32>::ld4(Wz, (long long)(k + kk) * H_N + c0 + 4, wz + 4);
                IO<F32>::ld4(Wr, (long long)(k + kk) * H_N + c0,     wr);
                IO<F32>::ld4(Wr, (long long)(k + kk) * H_N + c0 + 4, wr + 4);
                #pragma unroll
                for (int j = 0; j < 8; ++j) { az[j] += hvk * wz[j]; ar[j] += hvk * wr[j]; }
            }
        }
        {   // k = 260
            const float hvk = xh[row][KXH - 1];
            float wz[8], wr[8];
            IO<F32>::ld4(Wz, (long long)(KXH - 1) * H_N + c0,     wz);
            IO<F32>::ld4(Wz, (long long)(KXH - 1) * H_N + c0 + 4, wz + 4);
            IO<F32>::ld4(Wr, (long long)(KXH - 1) * H_N + c0,     wr);
            IO<F32>::ld4(Wr, (long long)(KXH - 1) * H_N + c0 + 4, wr + 4);
            #pragma unroll
            for (int j = 0; j < 8; ++j) { az[j] += hvk * wz[j]; ar[j] += hvk * wr[j]; }
        }

        float z[8], r[8];
        #pragma unroll
        for (int j = 0; j < 8; ++j) {
            z[j] = sigmoid_f(az[j]);
            r[j] = sigmoid_f(ar[j]);
            xg[row][NV_N + c0 + j] = r[j] * h[j];
        }
        __syncthreads();                        // bar2: xg complete

        // ---- pass 2: candidate h ----
        float ag[8];
        #pragma unroll
        for (int j = 0; j < 8; ++j) ag[j] = bhv[j];

        for (int k = 0; k < KXH - 1; k += 4) {
            const float4 gv = *reinterpret_cast<const float4*>(&xg[row][k]);
            #pragma unroll
            for (int kk = 0; kk < 4; ++kk) {
                const float gvk = (&gv.x)[kk];
                float wh[8];
                IO<F32>::ld4(Wh, (long long)(k + kk) * H_N + c0,     wh);
                IO<F32>::ld4(Wh, (long long)(k + kk) * H_N + c0 + 4, wh + 4);
                #pragma unroll
                for (int j = 0; j < 8; ++j) ag[j] += gvk * wh[j];
            }
        }
        {   // k = 260
            const float gvk = xg[row][KXH - 1];
            float wh[8];
            IO<F32>::ld4(Wh, (long long)(KXH - 1) * H_N + c0,     wh);
            IO<F32>::ld4(Wh, (long long)(KXH - 1) * H_N + c0 + 4, wh + 4);
            #pragma unroll
            for (int j = 0; j < 8; ++j) ag[j] += gvk * wh[j];
        }

        // ---- update, store, stash h(t+1) for next pass1 ----
        const bool active = (t < len);
        float hs[8];
        #pragma unroll
        for (int j = 0; j < 8; ++j) {
            float pre = tanh_f(ag[j]);
            float hn  = (1.f - z[j]) * h[j] + z[j] * pre;
            hn = active ? hn : h[j];
            h[j]  = hn;
            hs[j] = active ? hn : 0.f;
            smax[j] = active ? fmaxf(smax[j], hn) : smax[j];
            xh[row][NV_N + c0 + j] = hn;        // safe: no xh readers until bar1
        }
        IO<F32>::st4(out, OUT_ALLH + ((long long)b * T_N + t) * COLS + c0,     hs);
        IO<F32>::st4(out, OUT_ALLH + ((long long)b * T_N + t) * COLS + c0 + 4, hs + 4);
        if (t == len - 1) {
            IO<F32>::st4(out, (long long)b * H_N + c0,     h);
            IO<F32>::st4(out, (long long)b * H_N + c0 + 4, h + 4);
        }
    }

    // zero-fill all_h h-columns for t >= maxlen (rows with len<maxlen got
    // zeros in-loop); harness poisons d_out so every element must be written
    for (int t = maxlen; t < T_N; ++t) {
        IO<F32>::st4z(out, OUT_ALLH + ((long long)b * T_N + t) * COLS + c0);
        IO<F32>::st4z(out, OUT_ALLH + ((long long)b * T_N + t) * COLS + c0 + 4);
    }

    IO<F32>::st4(out, OUT_SEG + (long long)b * H_N + c0,     smax);
    IO<F32>::st4(out, OUT_SEG + (long long)b * H_N + c0 + 4, smax + 4);
}

extern "C" void kernel_launch(void* const* d_in, const int* in_sizes, int n_in,
                              void* d_out, int out_size, void* d_ws, size_t ws_size,
                              hipStream_t stream) {
    const void* x_seq  = d_in[0];
    const void* hidden = d_in[1];
    const void* tree   = d_in[2];
    const void* graph  = d_in[3];
    const int*  lens   = (const int*)d_in[4];
    const void* Wcs    = d_in[5];
    const void* bcs    = d_in[6];
    const void* Wz     = d_in[7];
    const void* bz     = d_in[8];
    const void* Wr     = d_in[9];
    const void* br     = d_in[10];
    const void* Wh     = d_in[11];
    const void* bh     = d_in[12];
    void* out = d_out;

    long long work = (long long)B_N * T_N * 64;
    int fill_blocks = (int)(work / 256);   // 51200

    // Launch BOTH dtype variants; each self-selects via detect_f32 and the
    // mismatching variant exits immediately. Deterministic work per call
    // => graph-capture safe.
    hipLaunchKernelGGL((latent_fill_kernel<true>),  dim3(fill_blocks), dim3(256), 0, stream,
                       tree, graph, lens, Wcs, out);
    hipLaunchKernelGGL((latent_fill_kernel<false>), dim3(fill_blocks), dim3(256), 0, stream,
                       tree, graph, lens, Wcs, out);

    hipLaunchKernelGGL((gru_kernel<true>), dim3(B_N / 8), dim3(256), 0, stream,
                       x_seq, hidden, graph, lens,
                       Wcs, bcs, Wz, bz, Wr, br, Wh, bh, out);
    hipLaunchKernelGGL((gru_kernel<false>), dim3(B_N / 8), dim3(256), 0, stream,
                       x_seq, hidden, graph, lens,
                       Wcs, bcs, Wz, bz, Wr, br, Wh, bh, out);
}

// Round 2
// 4572.866 us; speedup vs baseline: 1.2240x; 1.2240x over previous
//
#include <hip/hip_runtime.h>
#include <stdint.h>

// Problem constants (from reference)
#define B_N 2048
#define T_N 100
#define H_N 256
#define L_N 128
#define NV_N 5
#define COLS (H_N + 2 * 128)   // 512 columns of all_hidden_states

#define KXH 261                // NV + H rows of Wz/Wr/Wh
#define KPAD 264               // padded K (rows 261..263 are zero-h)
#define KCS 384                // H + L rows of Wcs
#define RB 8                   // batch rows per block
#define NKQ 8                  // k-split groups (== waves per block)
#define KQ_LEN 33              // ceil(261/8)

// Output element offsets, concatenated in return order:
// new_h [B,H], all_hidden_states [B,T,512], seg_rep [B,H]
static constexpr long long OUT_ALLH = (long long)B_N * H_N;                     // 524288
static constexpr long long OUT_SEG  = OUT_ALLH + (long long)B_N * T_N * COLS;   // 105381888

// dynamic LDS: Pz[8][8][256], Pr[8][8][256], xhT[264][8], xgT[264][8]
static constexpr int SMEM_FLOATS = 2 * NKQ * RB * H_N + 2 * KPAD * RB;          // 36992
static constexpr int SMEM_BYTES  = SMEM_FLOATS * 4;                             // 147968

__device__ __forceinline__ float bits2f(uint32_t u) {
    union { uint32_t u; float f; } v; v.u = u; return v.f;
}
__device__ __forceinline__ uint16_t f2bf(float f) {
    union { float f; uint32_t u; } v; v.f = f;
    uint32_t r = (v.u + 0x7FFFu + ((v.u >> 16) & 1u)) >> 16;   // round-nearest-even
    return (uint16_t)r;
}

// ---------------------------------------------------------------------------
// Runtime dtype detection (unchanged, verified): majority vote on the
// fp32-exponent field of 64 words of W_cs.
// ---------------------------------------------------------------------------
__device__ __forceinline__ int detect_f32(const uint32_t* __restrict__ w) {
    int cnt = 0;
    #pragma unroll 8
    for (int i = 0; i < 64; ++i) {
        uint32_t e = (w[i] >> 23) & 0xFFu;
        cnt += (e >= 97u && e <= 130u) ? 1 : 0;
    }
    return cnt >= 32 ? 1 : 0;
}

// ---------------------------------------------------------------------------
// Dtype-abstracted element access. Index units are ELEMENTS.
// ---------------------------------------------------------------------------
template <bool F32> struct IO;

template <> struct IO<true> {
    static __device__ __forceinline__ void ld4(const void* p, long long idx, float f[4]) {
        const float4 v = *(const float4*)((const float*)p + idx);
        f[0] = v.x; f[1] = v.y; f[2] = v.z; f[3] = v.w;
    }
    static __device__ __forceinline__ float ld1(const void* p, long long idx) {
        return ((const float*)p)[idx];
    }
    static __device__ __forceinline__ void st4(void* p, long long idx, const float f[4]) {
        *(float4*)((float*)p + idx) = make_float4(f[0], f[1], f[2], f[3]);
    }
    static __device__ __forceinline__ void st4z(void* p, long long idx) {
        *(float4*)((float*)p + idx) = make_float4(0.f, 0.f, 0.f, 0.f);
    }
};

template <> struct IO<false> {
    static __device__ __forceinline__ void ld4(const void* p, long long idx, float f[4]) {
        uint2 u = *(const uint2*)((const uint16_t*)p + idx);
        f[0] = bits2f(u.x << 16);
        f[1] = bits2f(u.x & 0xFFFF0000u);
        f[2] = bits2f(u.y << 16);
        f[3] = bits2f(u.y & 0xFFFF0000u);
    }
    static __device__ __forceinline__ float ld1(const void* p, long long idx) {
        return bits2f(((uint32_t)((const uint16_t*)p)[idx]) << 16);
    }
    static __device__ __forceinline__ void st4(void* p, long long idx, const float f[4]) {
        uint2 u;
        u.x = (uint32_t)f2bf(f[0]) | ((uint32_t)f2bf(f[1]) << 16);
        u.y = (uint32_t)f2bf(f[2]) | ((uint32_t)f2bf(f[3]) << 16);
        *(uint2*)((uint16_t*)p + idx) = u;
    }
    static __device__ __forceinline__ void st4z(void* p, long long idx) {
        *(uint2*)((uint16_t*)p + idx) = make_uint2(0u, 0u);
    }
};

__device__ __forceinline__ float sigmoid_f(float x) {
    x = fminf(fmaxf(x, -30.f), 30.f);
    return 1.f / (1.f + __expf(-x));
}
__device__ __forceinline__ float tanh_f(float x) {
    x = fminf(fmaxf(x, -15.f), 15.f);
    float e = __expf(-2.f * x);
    return (1.f - e) / (1.f + e);
}

// ---------------------------------------------------------------------------
// Kernel 1: fill all_hidden_states[:, :, 256:512] with masked tree/graph
// broadcast (zeros at t >= len). Unchanged from verified kernel.
// ---------------------------------------------------------------------------
template <bool F32>
__global__ __launch_bounds__(256) void latent_fill_kernel(
    const void* __restrict__ tree,
    const void* __restrict__ graph,
    const int* __restrict__ lengths,
    const void* __restrict__ Wcs_detect,
    void* __restrict__ out)
{
    __shared__ int s_is32;
    if (threadIdx.x == 0) s_is32 = detect_f32((const uint32_t*)Wcs_detect);
    __syncthreads();
    if ((s_is32 != 0) != F32) return;

    long long idx = (long long)blockIdx.x * 256 + threadIdx.x;   // 0 .. B*T*64
    int c = ((int)(idx & 63)) * 4;           // 0..252 within latent cols
    long long bt = idx >> 6;                 // b*T + t
    int t = (int)(bt % T_N);
    int b = (int)(bt / T_N);

    long long dst = OUT_ALLH + bt * COLS + H_N + c;
    if (t < lengths[b]) {
        float v[4];
        if (c < L_N) IO<F32>::ld4(tree, (long long)b * L_N + c, v);
        else         IO<F32>::ld4(graph, (long long)b * L_N + (c - L_N), v);
        IO<F32>::st4(out, dst, v);
    } else {
        IO<F32>::st4z(out, dst);
    }
}

// ---------------------------------------------------------------------------
// Kernel 2: k-split block-GEMM GRU.
//   512 threads = 64 col-groups (4 cols) x 8 k-groups.
//   GEMM phases: wave w = k-group w, thread accumulates partials for ALL 8
//     rows x its 4 cols over ~33 k-rows -> each b128 weight load feeds 32
//     FMAs; weight bytes per block per step = 802 KB (the minimum).
//   Gate phases: wave w = row-owner w (owns row w, all 64 lanes cover the
//     256 cols); h and z stay in owner registers across the step.
//   h/x and r*h/x live transposed in LDS as xhT/xgT[k][r] so GEMM-phase
//     reads are same-address b128 broadcasts (conflict-free).
//   4 barriers/step: pass1 -> B1 -> gates(z,r)+write xgT -> B2 -> pass2
//     -> B3 -> reduce+update+stores+stage x(t+1) -> B4.
//   K padded 261->264 with zero h-rows (weight index clamped) for a
//     compile-time trip count of 33 in both GEMM loops.
// ---------------------------------------------------------------------------
template <bool F32>
__global__ __launch_bounds__(512, 2) void gru_kernel(
    const void* __restrict__ x_seq,
    const void* __restrict__ hidden,
    const void* __restrict__ graph,
    const int* __restrict__ lengths,
    const void* __restrict__ Wcs, const void* __restrict__ bcs,
    const void* __restrict__ Wz,  const void* __restrict__ bz,
    const void* __restrict__ Wr,  const void* __restrict__ br,
    const void* __restrict__ Wh,  const void* __restrict__ bh,
    void* __restrict__ out)
{
    extern __shared__ float smem[];
    float* Pz  = smem;                      // [NKQ][RB][H_N]
    float* Pr  = Pz  + NKQ * RB * H_N;      // [NKQ][RB][H_N]
    float* xhT = Pr  + NKQ * RB * H_N;      // [KPAD][RB]  (k<5: x, k>=5: h)
    float* xgT = xhT + KPAD * RB;           // [KPAD][RB]  (k<5: x, k>=5: r*h)

    __shared__ int s_is32;
    __shared__ int s_len[RB];
    if (threadIdx.x == 0) s_is32 = detect_f32((const uint32_t*)Wcs);
    __syncthreads();
    if ((s_is32 != 0) != F32) return;

    const int tid  = threadIdx.x;
    const int wv   = tid >> 6;       // k-group in GEMM phases, row-owner in gates
    const int lane = tid & 63;
    const int c0   = lane * 4;       // this thread's 4 columns

    if (tid < RB) {
        int L = lengths[blockIdx.x * RB + tid];
        s_len[tid] = min(max(L, 1), T_N);
    }
    // zero the padded h-rows 261..263 once
    if (tid < (KPAD - KXH) * RB) {
        int p = tid / RB, r = tid - p * RB;
        xhT[(KXH + p) * RB + r] = 0.f;
        xgT[(KXH + p) * RB + r] = 0.f;
    }
    __syncthreads();

    const int b0  = blockIdx.x * RB;
    const int bo  = b0 + wv;                 // owner batch row
    const int len = s_len[wv];
    int maxlen = 1;
    #pragma unroll
    for (int i = 0; i < RB; ++i) maxlen = max(maxlen, s_len[i]);

    // ---- stage [hidden, graph] into Pz region (alias), stride 388 ----
    {
        float* cs = Pz;
        for (int i = tid; i < RB * KCS; i += 512) {
            int r = i / KCS;
            int k = i - r * KCS;
            int bb = b0 + r;
            float v = (k < H_N) ? IO<F32>::ld1(hidden, (long long)bb * H_N + k)
                                : IO<F32>::ld1(graph,  (long long)bb * L_N + (k - H_N));
            cs[r * 388 + k] = v;
        }
    }
    __syncthreads();

    // ---- h0 = relu(cs[wv] @ Wcs + bcs): owner computes its row, full K ----
    float h[4];
    {
        const float* cs = Pz;
        float acc[4];
        IO<F32>::ld4(bcs, c0, acc);
        for (int k = 0; k < KCS; k += 4) {
            const float4 hv = *reinterpret_cast<const float4*>(&cs[wv * 388 + k]);
            float hvv[4] = {hv.x, hv.y, hv.z, hv.w};
            #pragma unroll
            for (int kk = 0; kk < 4; ++kk) {
                float w[4];
                IO<F32>::ld4(Wcs, (long long)(k + kk) * H_N + c0, w);
                #pragma unroll
                for (int j = 0; j < 4; ++j) acc[j] += hvv[kk] * w[j];
            }
        }
        #pragma unroll
        for (int j = 0; j < 4; ++j) h[j] = fmaxf(acc[j], 0.f);
    }
    __syncthreads();   // all cs reads done before Pz is reused as partials

    // ---- biases (owner registers, loop-invariant) ----
    float bzv[4], brv[4], bhv[4];
    IO<F32>::ld4(bz, c0, bzv);
    IO<F32>::ld4(br, c0, brv);
    IO<F32>::ld4(bh, c0, bhv);

    float smax[4] = {-1e30f, -1e30f, -1e30f, -1e30f};

    // ---- x prefetch: threads 0..39 own one (row, nuc) slot each ----
    const int xr = tid / NV_N;
    const int xi = tid - xr * NV_N;
    float xv = 0.f;
    if (tid < RB * NV_N)
        xv = IO<F32>::ld1(x_seq, ((long long)(b0 + xr) * T_N + 0) * NV_N + xi);

    // ---- init xhT/xgT: x(0) part + h0 part ----
    if (tid < RB * NV_N) {
        xhT[xi * RB + xr] = xv;
        xgT[xi * RB + xr] = xv;
    }
    #pragma unroll
    for (int j = 0; j < 4; ++j)
        xhT[(NV_N + c0 + j) * RB + wv] = h[j];
    if (tid < RB * NV_N) {
        int tn = (1 < T_N) ? 1 : 0;
        xv = IO<F32>::ld1(x_seq, ((long long)(b0 + xr) * T_N + tn) * NV_N + xi);
    }
    __syncthreads();

    const int k0 = wv * KQ_LEN;

    float z[4];   // persists pass1 -> update

    for (int t = 0; t < maxlen; ++t) {
        // ================= pass 1: partial z,r over this wave's k-range ======
        float az[8][4], ar[8][4];
        #pragma unroll
        for (int r = 0; r < 8; ++r)
            #pragma unroll
            for (int j = 0; j < 4; ++j) { az[r][j] = 0.f; ar[r][j] = 0.f; }

        #pragma unroll 3
        for (int kk = 0; kk < KQ_LEN; ++kk) {
            const int k  = k0 + kk;                 // < 264
            const int kl = (k <= KXH - 1) ? k : (KXH - 1);   // clamp W row (pad h==0)
            const float4 a = *reinterpret_cast<const float4*>(&xhT[k * RB + 0]);
            const float4 b = *reinterpret_cast<const float4*>(&xhT[k * RB + 4]);
            float hv[8] = {a.x, a.y, a.z, a.w, b.x, b.y, b.z, b.w};
            float wz4[4], wr4[4];
            IO<F32>::ld4(Wz, (long long)kl * H_N + c0, wz4);
            IO<F32>::ld4(Wr, (long long)kl * H_N + c0, wr4);
            #pragma unroll
            for (int r = 0; r < 8; ++r) {
                #pragma unroll
                for (int j = 0; j < 4; ++j) {
                    az[r][j] += hv[r] * wz4[j];
                    ar[r][j] += hv[r] * wr4[j];
                }
            }
        }
        #pragma unroll
        for (int r = 0; r < 8; ++r) {
            *reinterpret_cast<float4*>(&Pz[(wv * RB + r) * H_N + c0]) =
                make_float4(az[r][0], az[r][1], az[r][2], az[r][3]);
            *reinterpret_cast<float4*>(&Pr[(wv * RB + r) * H_N + c0]) =
                make_float4(ar[r][0], ar[r][1], ar[r][2], ar[r][3]);
        }
        __syncthreads();                           // B1

        // ================= gates z,r (owner: row wv, cols c0..c0+3) ==========
        {
            float sz[4] = {bzv[0], bzv[1], bzv[2], bzv[3]};
            float sr[4] = {brv[0], brv[1], brv[2], brv[3]};
            #pragma unroll
            for (int kq = 0; kq < NKQ; ++kq) {
                const float4 pz = *reinterpret_cast<const float4*>(&Pz[(kq * RB + wv) * H_N + c0]);
                const float4 pr = *reinterpret_cast<const float4*>(&Pr[(kq * RB + wv) * H_N + c0]);
                sz[0] += pz.x; sz[1] += pz.y; sz[2] += pz.z; sz[3] += pz.w;
                sr[0] += pr.x; sr[1] += pr.y; sr[2] += pr.z; sr[3] += pr.w;
            }
            #pragma unroll
            for (int j = 0; j < 4; ++j) {
                z[j] = sigmoid_f(sz[j]);
                float rr = sigmoid_f(sr[j]);
                xgT[(NV_N + c0 + j) * RB + wv] = rr * h[j];
            }
        }
        __syncthreads();                           // B2

        // ================= pass 2: partial candidate-h =======================
        float ag[8][4];
        #pragma unroll
        for (int r = 0; r < 8; ++r)
            #pragma unroll
            for (int j = 0; j < 4; ++j) ag[r][j] = 0.f;

        #pragma unroll 3
        for (int kk = 0; kk < KQ_LEN; ++kk) {
            const int k  = k0 + kk;
            const int kl = (k <= KXH - 1) ? k : (KXH - 1);
            const float4 a = *reinterpret_cast<const float4*>(&xgT[k * RB + 0]);
            const float4 b = *reinterpret_cast<const float4*>(&xgT[k * RB + 4]);
            float gv[8] = {a.x, a.y, a.z, a.w, b.x, b.y, b.z, b.w};
            float wh4[4];
            IO<F32>::ld4(Wh, (long long)kl * H_N + c0, wh4);
            #pragma unroll
            for (int r = 0; r < 8; ++r) {
                #pragma unroll
                for (int j = 0; j < 4; ++j) ag[r][j] += gv[r] * wh4[j];
            }
        }
        #pragma unroll
        for (int r = 0; r < 8; ++r)
            *reinterpret_cast<float4*>(&Pz[(wv * RB + r) * H_N + c0]) =
                make_float4(ag[r][0], ag[r][1], ag[r][2], ag[r][3]);
        __syncthreads();                           // B3

        // ================= reduce + update + stores (owner) ==================
        {
            float sg[4] = {bhv[0], bhv[1], bhv[2], bhv[3]};
            #pragma unroll
            for (int kq = 0; kq < NKQ; ++kq) {
                const float4 pg = *reinterpret_cast<const float4*>(&Pz[(kq * RB + wv) * H_N + c0]);
                sg[0] += pg.x; sg[1] += pg.y; sg[2] += pg.z; sg[3] += pg.w;
            }
            const bool active = (t < len);
            float hs[4];
            #pragma unroll
            for (int j = 0; j < 4; ++j) {
                float pre = tanh_f(sg[j]);
                float hn  = (1.f - z[j]) * h[j] + z[j] * pre;
                hn = active ? hn : h[j];
                h[j]  = hn;
                hs[j] = active ? hn : 0.f;
                smax[j] = active ? fmaxf(smax[j], hn) : smax[j];
                xhT[(NV_N + c0 + j) * RB + wv] = hn;
            }
            IO<F32>::st4(out, OUT_ALLH + ((long long)bo * T_N + t) * COLS + c0, hs);
            if (t == len - 1)
                IO<F32>::st4(out, (long long)bo * H_N + c0, h);
        }
        // stage x(t+1) and prefetch x(t+2)
        if (tid < RB * NV_N) {
            xhT[xi * RB + xr] = xv;
            xgT[xi * RB + xr] = xv;
            int tn = (t + 2 < T_N) ? (t + 2) : (T_N - 1);
            xv = IO<F32>::ld1(x_seq, ((long long)(b0 + xr) * T_N + tn) * NV_N + xi);
        }
        __syncthreads();                           // B4
    }

    // zero-fill all_h h-columns for t >= maxlen (rows with len<maxlen got
    // zeros in-loop); harness poisons d_out so every element must be written
    for (int t = maxlen; t < T_N; ++t)
        IO<F32>::st4z(out, OUT_ALLH + ((long long)bo * T_N + t) * COLS + c0);

    IO<F32>::st4(out, OUT_SEG + (long long)bo * H_N + c0, smax);
}

extern "C" void kernel_launch(void* const* d_in, const int* in_sizes, int n_in,
                              void* d_out, int out_size, void* d_ws, size_t ws_size,
                              hipStream_t stream) {
    const void* x_seq  = d_in[0];
    const void* hidden = d_in[1];
    const void* tree   = d_in[2];
    const void* graph  = d_in[3];
    const int*  lens   = (const int*)d_in[4];
    const void* Wcs    = d_in[5];
    const void* bcs    = d_in[6];
    const void* Wz     = d_in[7];
    const void* bz     = d_in[8];
    const void* Wr     = d_in[9];
    const void* br     = d_in[10];
    const void* Wh     = d_in[11];
    const void* bh     = d_in[12];
    void* out = d_out;

    // allow >64KB dynamic LDS (once per process; host-side, capture-safe)
    static bool attr_set = false;
    if (!attr_set) {
        (void)hipFuncSetAttribute(reinterpret_cast<const void*>(&gru_kernel<true>),
                                  hipFuncAttributeMaxDynamicSharedMemorySize, SMEM_BYTES);
        (void)hipFuncSetAttribute(reinterpret_cast<const void*>(&gru_kernel<false>),
                                  hipFuncAttributeMaxDynamicSharedMemorySize, SMEM_BYTES);
        attr_set = true;
    }

    long long work = (long long)B_N * T_N * 64;
    int fill_blocks = (int)(work / 256);   // 51200

    // Launch BOTH dtype variants; each self-selects via detect_f32 and the
    // mismatching variant exits immediately. Deterministic work per call
    // => graph-capture safe.
    hipLaunchKernelGGL((latent_fill_kernel<true>),  dim3(fill_blocks), dim3(256), 0, stream,
                       tree, graph, lens, Wcs, out);
    hipLaunchKernelGGL((latent_fill_kernel<false>), dim3(fill_blocks), dim3(256), 0, stream,
                       tree, graph, lens, Wcs, out);

    hipLaunchKernelGGL((gru_kernel<true>), dim3(B_N / RB), dim3(512), SMEM_BYTES, stream,
                       x_seq, hidden, graph, lens,
                       Wcs, bcs, Wz, bz, Wr, br, Wh, bh, out);
    hipLaunchKernelGGL((gru_kernel<false>), dim3(B_N / RB), dim3(512), SMEM_BYTES, stream,
                       x_seq, hidden, graph, lens,
                       Wcs, bcs, Wz, bz, Wr, br, Wh, bh, out);
}

// Round 3
// 4498.830 us; speedup vs baseline: 1.2442x; 1.0165x over previous
//
#include <hip/hip_runtime.h>
#include <stdint.h>

// Problem constants (from reference)
#define B_N 2048
#define T_N 100
#define H_N 256
#define L_N 128
#define NV_N 5
#define COLS (H_N + 2 * 128)   // 512 columns of all_hidden_states

#define KXH 261                // NV + H rows of Wz/Wr/Wh
#define KPAD 264               // padded K (rows 261..263 are zero-h)
#define KCS 384                // H + L rows of Wcs
#define RB 8                   // batch rows per block
#define NKQ 8                  // k-split groups (== waves per block)
#define KQ_LEN 33              // 264 / 8
#define CH 11                  // chunk size: 3 chunks of 11 per k-slice

// Output element offsets, concatenated in return order:
// new_h [B,H], all_hidden_states [B,T,512], seg_rep [B,H]
static constexpr long long OUT_ALLH = (long long)B_N * H_N;                     // 524288
static constexpr long long OUT_SEG  = OUT_ALLH + (long long)B_N * T_N * COLS;   // 105381888

// dynamic LDS: Pz[8][8][256], Pr[8][8][256], xhT[264][8], xgT[264][8]
static constexpr int SMEM_FLOATS = 2 * NKQ * RB * H_N + 2 * KPAD * RB;          // 36992
static constexpr int SMEM_BYTES  = SMEM_FLOATS * 4;                             // 147968

__device__ __forceinline__ float bits2f(uint32_t u) {
    union { uint32_t u; float f; } v; v.u = u; return v.f;
}
__device__ __forceinline__ uint16_t f2bf(float f) {
    union { float f; uint32_t u; } v; v.f = f;
    uint32_t r = (v.u + 0x7FFFu + ((v.u >> 16) & 1u)) >> 16;   // round-nearest-even
    return (uint16_t)r;
}

// ---------------------------------------------------------------------------
// Runtime dtype detection (unchanged, verified): majority vote on the
// fp32-exponent field of 64 words of W_cs.
// ---------------------------------------------------------------------------
__device__ __forceinline__ int detect_f32(const uint32_t* __restrict__ w) {
    int cnt = 0;
    #pragma unroll 8
    for (int i = 0; i < 64; ++i) {
        uint32_t e = (w[i] >> 23) & 0xFFu;
        cnt += (e >= 97u && e <= 130u) ? 1 : 0;
    }
    return cnt >= 32 ? 1 : 0;
}

// ---------------------------------------------------------------------------
// Dtype-abstracted element access. Index units are ELEMENTS.
// raw/cvt pair: ldraw issues the load into a raw register payload; cvt
// unpacks later (lets us batch-issue many loads before consuming).
// ---------------------------------------------------------------------------
template <bool F32> struct IO;

template <> struct IO<true> {
    using Raw = float4;
    static __device__ __forceinline__ Raw ldraw(const void* p, long long idx) {
        return *(const float4*)((const float*)p + idx);
    }
    static __device__ __forceinline__ void cvt(const Raw& u, float f[4]) {
        f[0] = u.x; f[1] = u.y; f[2] = u.z; f[3] = u.w;
    }
    static __device__ __forceinline__ void ld4(const void* p, long long idx, float f[4]) {
        const float4 v = *(const float4*)((const float*)p + idx);
        f[0] = v.x; f[1] = v.y; f[2] = v.z; f[3] = v.w;
    }
    static __device__ __forceinline__ float ld1(const void* p, long long idx) {
        return ((const float*)p)[idx];
    }
    static __device__ __forceinline__ void st4(void* p, long long idx, const float f[4]) {
        *(float4*)((float*)p + idx) = make_float4(f[0], f[1], f[2], f[3]);
    }
    static __device__ __forceinline__ void st4z(void* p, long long idx) {
        *(float4*)((float*)p + idx) = make_float4(0.f, 0.f, 0.f, 0.f);
    }
};

template <> struct IO<false> {
    using Raw = uint2;
    static __device__ __forceinline__ Raw ldraw(const void* p, long long idx) {
        return *(const uint2*)((const uint16_t*)p + idx);
    }
    static __device__ __forceinline__ void cvt(const Raw& u, float f[4]) {
        f[0] = bits2f(u.x << 16);
        f[1] = bits2f(u.x & 0xFFFF0000u);
        f[2] = bits2f(u.y << 16);
        f[3] = bits2f(u.y & 0xFFFF0000u);
    }
    static __device__ __forceinline__ void ld4(const void* p, long long idx, float f[4]) {
        uint2 u = *(const uint2*)((const uint16_t*)p + idx);
        cvt(u, f);
    }
    static __device__ __forceinline__ float ld1(const void* p, long long idx) {
        return bits2f(((uint32_t)((const uint16_t*)p)[idx]) << 16);
    }
    static __device__ __forceinline__ void st4(void* p, long long idx, const float f[4]) {
        uint2 u;
        u.x = (uint32_t)f2bf(f[0]) | ((uint32_t)f2bf(f[1]) << 16);
        u.y = (uint32_t)f2bf(f[2]) | ((uint32_t)f2bf(f[3]) << 16);
        *(uint2*)((uint16_t*)p + idx) = u;
    }
    static __device__ __forceinline__ void st4z(void* p, long long idx) {
        *(uint2*)((uint16_t*)p + idx) = make_uint2(0u, 0u);
    }
};

__device__ __forceinline__ float sigmoid_f(float x) {
    x = fminf(fmaxf(x, -30.f), 30.f);
    return 1.f / (1.f + __expf(-x));
}
__device__ __forceinline__ float tanh_f(float x) {
    x = fminf(fmaxf(x, -15.f), 15.f);
    float e = __expf(-2.f * x);
    return (1.f - e) / (1.f + e);
}

// ---------------------------------------------------------------------------
// Kernel 1: fill all_hidden_states[:, :, 256:512] with masked tree/graph
// broadcast (zeros at t >= len). Widened to 8 elements / thread.
// ---------------------------------------------------------------------------
template <bool F32>
__global__ __launch_bounds__(256) void latent_fill_kernel(
    const void* __restrict__ tree,
    const void* __restrict__ graph,
    const int* __restrict__ lengths,
    const void* __restrict__ Wcs_detect,
    void* __restrict__ out)
{
    __shared__ int s_is32;
    if (threadIdx.x == 0) s_is32 = detect_f32((const uint32_t*)Wcs_detect);
    __syncthreads();
    if ((s_is32 != 0) != F32) return;

    long long idx = (long long)blockIdx.x * 256 + threadIdx.x;   // 0 .. B*T*32
    int c = ((int)(idx & 31)) * 8;           // 0..248 within latent cols
    long long bt = idx >> 5;                 // b*T + t
    int t = (int)(bt % T_N);
    int b = (int)(bt / T_N);

    long long dst = OUT_ALLH + bt * COLS + H_N + c;
    if (t < lengths[b]) {
        float v[8];
        if (c < L_N) {
            IO<F32>::ld4(tree, (long long)b * L_N + c, v);
            IO<F32>::ld4(tree, (long long)b * L_N + c + 4, v + 4);
        } else {
            IO<F32>::ld4(graph, (long long)b * L_N + (c - L_N), v);
            IO<F32>::ld4(graph, (long long)b * L_N + (c - L_N) + 4, v + 4);
        }
        IO<F32>::st4(out, dst, v);
        IO<F32>::st4(out, dst + 4, v + 4);
    } else {
        IO<F32>::st4z(out, dst);
        IO<F32>::st4z(out, dst + 4);
    }
}

// ---------------------------------------------------------------------------
// Kernel 2: k-split block-GEMM GRU with batch-issue load chunking.
//   512 threads = 64 col-groups (4 cols) x 8 k-groups.
//   Each k-slice (33 rows) is processed as 3 chunks of 11: per chunk, ALL
//   weight loads are issued first into raw register arrays (static indices),
//   then converted+FMA'd. 22 loads in flight per wave hides L2 latency
//   (the round-2 version had ~6 in flight -> 82% stall, VALUBusy 18%).
//   Everything else (layout, barriers, gates, stores) identical to the
//   verified round-2 kernel.
// ---------------------------------------------------------------------------
template <bool F32>
__global__ __launch_bounds__(512, 2) void gru_kernel(
    const void* __restrict__ x_seq,
    const void* __restrict__ hidden,
    const void* __restrict__ graph,
    const int* __restrict__ lengths,
    const void* __restrict__ Wcs, const void* __restrict__ bcs,
    const void* __restrict__ Wz,  const void* __restrict__ bz,
    const void* __restrict__ Wr,  const void* __restrict__ br,
    const void* __restrict__ Wh,  const void* __restrict__ bh,
    void* __restrict__ out)
{
    extern __shared__ float smem[];
    float* Pz  = smem;                      // [NKQ][RB][H_N]
    float* Pr  = Pz  + NKQ * RB * H_N;      // [NKQ][RB][H_N]
    float* xhT = Pr  + NKQ * RB * H_N;      // [KPAD][RB]  (k<5: x, k>=5: h)
    float* xgT = xhT + KPAD * RB;           // [KPAD][RB]  (k<5: x, k>=5: r*h)

    __shared__ int s_is32;
    __shared__ int s_len[RB];
    if (threadIdx.x == 0) s_is32 = detect_f32((const uint32_t*)Wcs);
    __syncthreads();
    if ((s_is32 != 0) != F32) return;

    const int tid  = threadIdx.x;
    const int wv   = tid >> 6;       // k-group in GEMM phases, row-owner in gates
    const int lane = tid & 63;
    const int c0   = lane * 4;       // this thread's 4 columns

    if (tid < RB) {
        int L = lengths[blockIdx.x * RB + tid];
        s_len[tid] = min(max(L, 1), T_N);
    }
    // zero the padded h-rows 261..263 once
    if (tid < (KPAD - KXH) * RB) {
        int p = tid / RB, r = tid - p * RB;
        xhT[(KXH + p) * RB + r] = 0.f;
        xgT[(KXH + p) * RB + r] = 0.f;
    }
    __syncthreads();

    const int b0  = blockIdx.x * RB;
    const int bo  = b0 + wv;                 // owner batch row
    const int len = s_len[wv];
    int maxlen = 1;
    #pragma unroll
    for (int i = 0; i < RB; ++i) maxlen = max(maxlen, s_len[i]);

    // ---- stage [hidden, graph] into Pz region (alias), stride 388 ----
    {
        float* cs = Pz;
        for (int i = tid; i < RB * KCS; i += 512) {
            int r = i / KCS;
            int k = i - r * KCS;
            int bb = b0 + r;
            float v = (k < H_N) ? IO<F32>::ld1(hidden, (long long)bb * H_N + k)
                                : IO<F32>::ld1(graph,  (long long)bb * L_N + (k - H_N));
            cs[r * 388 + k] = v;
        }
    }
    __syncthreads();

    // ---- h0 = relu(cs[wv] @ Wcs + bcs): owner computes its row, full K ----
    float h[4];
    {
        const float* cs = Pz;
        float acc[4];
        IO<F32>::ld4(bcs, c0, acc);
        for (int k = 0; k < KCS; k += 4) {
            const float4 hv = *reinterpret_cast<const float4*>(&cs[wv * 388 + k]);
            float hvv[4] = {hv.x, hv.y, hv.z, hv.w};
            #pragma unroll
            for (int kk = 0; kk < 4; ++kk) {
                float w[4];
                IO<F32>::ld4(Wcs, (long long)(k + kk) * H_N + c0, w);
                #pragma unroll
                for (int j = 0; j < 4; ++j) acc[j] += hvv[kk] * w[j];
            }
        }
        #pragma unroll
        for (int j = 0; j < 4; ++j) h[j] = fmaxf(acc[j], 0.f);
    }
    __syncthreads();   // all cs reads done before Pz is reused as partials

    // ---- biases (owner registers, loop-invariant) ----
    float bzv[4], brv[4], bhv[4];
    IO<F32>::ld4(bz, c0, bzv);
    IO<F32>::ld4(br, c0, brv);
    IO<F32>::ld4(bh, c0, bhv);

    float smax[4] = {-1e30f, -1e30f, -1e30f, -1e30f};

    // ---- x prefetch: threads 0..39 own one (row, nuc) slot each ----
    const int xr = tid / NV_N;
    const int xi = tid - xr * NV_N;
    float xv = 0.f;
    if (tid < RB * NV_N)
        xv = IO<F32>::ld1(x_seq, ((long long)(b0 + xr) * T_N + 0) * NV_N + xi);

    // ---- init xhT/xgT: x(0) part + h0 part ----
    if (tid < RB * NV_N) {
        xhT[xi * RB + xr] = xv;
        xgT[xi * RB + xr] = xv;
    }
    #pragma unroll
    for (int j = 0; j < 4; ++j)
        xhT[(NV_N + c0 + j) * RB + wv] = h[j];
    if (tid < RB * NV_N) {
        int tn = (1 < T_N) ? 1 : 0;
        xv = IO<F32>::ld1(x_seq, ((long long)(b0 + xr) * T_N + tn) * NV_N + xi);
    }
    __syncthreads();

    const int k0 = wv * KQ_LEN;

    float z[4];   // persists pass1 -> update

    for (int t = 0; t < maxlen; ++t) {
        // ================= pass 1: partial z,r over this wave's k-range ======
        float az[8][4], ar[8][4];
        #pragma unroll
        for (int r = 0; r < 8; ++r)
            #pragma unroll
            for (int j = 0; j < 4; ++j) { az[r][j] = 0.f; ar[r][j] = 0.f; }

        #pragma unroll 1
        for (int ch = 0; ch < 3; ++ch) {
            const int kb = k0 + ch * CH;
            typename IO<F32>::Raw rz[CH], rr[CH];
            #pragma unroll
            for (int i = 0; i < CH; ++i) {
                const int k  = kb + i;
                const int kl = (k <= KXH - 1) ? k : (KXH - 1);   // pad rows: h==0
                rz[i] = IO<F32>::ldraw(Wz, (long long)kl * H_N + c0);
                rr[i] = IO<F32>::ldraw(Wr, (long long)kl * H_N + c0);
            }
            #pragma unroll
            for (int i = 0; i < CH; ++i) {
                const int k = kb + i;
                const float4 a = *reinterpret_cast<const float4*>(&xhT[k * RB + 0]);
                const float4 b = *reinterpret_cast<const float4*>(&xhT[k * RB + 4]);
                float hv[8] = {a.x, a.y, a.z, a.w, b.x, b.y, b.z, b.w};
                float wz4[4], wr4[4];
                IO<F32>::cvt(rz[i], wz4);
                IO<F32>::cvt(rr[i], wr4);
                #pragma unroll
                for (int r = 0; r < 8; ++r) {
                    #pragma unroll
                    for (int j = 0; j < 4; ++j) {
                        az[r][j] += hv[r] * wz4[j];
                        ar[r][j] += hv[r] * wr4[j];
                    }
                }
            }
        }
        #pragma unroll
        for (int r = 0; r < 8; ++r) {
            *reinterpret_cast<float4*>(&Pz[(wv * RB + r) * H_N + c0]) =
                make_float4(az[r][0], az[r][1], az[r][2], az[r][3]);
            *reinterpret_cast<float4*>(&Pr[(wv * RB + r) * H_N + c0]) =
                make_float4(ar[r][0], ar[r][1], ar[r][2], ar[r][3]);
        }
        __syncthreads();                           // B1

        // ================= gates z,r (owner: row wv, cols c0..c0+3) ==========
        {
            float sz[4] = {bzv[0], bzv[1], bzv[2], bzv[3]};
            float sr[4] = {brv[0], brv[1], brv[2], brv[3]};
            #pragma unroll
            for (int kq = 0; kq < NKQ; ++kq) {
                const float4 pz = *reinterpret_cast<const float4*>(&Pz[(kq * RB + wv) * H_N + c0]);
                const float4 pr = *reinterpret_cast<const float4*>(&Pr[(kq * RB + wv) * H_N + c0]);
                sz[0] += pz.x; sz[1] += pz.y; sz[2] += pz.z; sz[3] += pz.w;
                sr[0] += pr.x; sr[1] += pr.y; sr[2] += pr.z; sr[3] += pr.w;
            }
            #pragma unroll
            for (int j = 0; j < 4; ++j) {
                z[j] = sigmoid_f(sz[j]);
                float rr = sigmoid_f(sr[j]);
                xgT[(NV_N + c0 + j) * RB + wv] = rr * h[j];
            }
        }
        __syncthreads();                           // B2

        // ================= pass 2: partial candidate-h =======================
        float ag[8][4];
        #pragma unroll
        for (int r = 0; r < 8; ++r)
            #pragma unroll
            for (int j = 0; j < 4; ++j) ag[r][j] = 0.f;

        #pragma unroll 1
        for (int ch = 0; ch < 3; ++ch) {
            const int kb = k0 + ch * CH;
            typename IO<F32>::Raw rh[CH];
            #pragma unroll
            for (int i = 0; i < CH; ++i) {
                const int k  = kb + i;
                const int kl = (k <= KXH - 1) ? k : (KXH - 1);
                rh[i] = IO<F32>::ldraw(Wh, (long long)kl * H_N + c0);
            }
            #pragma unroll
            for (int i = 0; i < CH; ++i) {
                const int k = kb + i;
                const float4 a = *reinterpret_cast<const float4*>(&xgT[k * RB + 0]);
                const float4 b = *reinterpret_cast<const float4*>(&xgT[k * RB + 4]);
                float gv[8] = {a.x, a.y, a.z, a.w, b.x, b.y, b.z, b.w};
                float wh4[4];
                IO<F32>::cvt(rh[i], wh4);
                #pragma unroll
                for (int r = 0; r < 8; ++r) {
                    #pragma unroll
                    for (int j = 0; j < 4; ++j) ag[r][j] += gv[r] * wh4[j];
                }
            }
        }
        #pragma unroll
        for (int r = 0; r < 8; ++r)
            *reinterpret_cast<float4*>(&Pz[(wv * RB + r) * H_N + c0]) =
                make_float4(ag[r][0], ag[r][1], ag[r][2], ag[r][3]);
        __syncthreads();                           // B3

        // ================= reduce + update + stores (owner) ==================
        {
            float sg[4] = {bhv[0], bhv[1], bhv[2], bhv[3]};
            #pragma unroll
            for (int kq = 0; kq < NKQ; ++kq) {
                const float4 pg = *reinterpret_cast<const float4*>(&Pz[(kq * RB + wv) * H_N + c0]);
                sg[0] += pg.x; sg[1] += pg.y; sg[2] += pg.z; sg[3] += pg.w;
            }
            const bool active = (t < len);
            float hs[4];
            #pragma unroll
            for (int j = 0; j < 4; ++j) {
                float pre = tanh_f(sg[j]);
                float hn  = (1.f - z[j]) * h[j] + z[j] * pre;
                hn = active ? hn : h[j];
                h[j]  = hn;
                hs[j] = active ? hn : 0.f;
                smax[j] = active ? fmaxf(smax[j], hn) : smax[j];
                xhT[(NV_N + c0 + j) * RB + wv] = hn;
            }
            IO<F32>::st4(out, OUT_ALLH + ((long long)bo * T_N + t) * COLS + c0, hs);
            if (t == len - 1)
                IO<F32>::st4(out, (long long)bo * H_N + c0, h);
        }
        // stage x(t+1) and prefetch x(t+2)
        if (tid < RB * NV_N) {
            xhT[xi * RB + xr] = xv;
            xgT[xi * RB + xr] = xv;
            int tn = (t + 2 < T_N) ? (t + 2) : (T_N - 1);
            xv = IO<F32>::ld1(x_seq, ((long long)(b0 + xr) * T_N + tn) * NV_N + xi);
        }
        __syncthreads();                           // B4
    }

    // zero-fill all_h h-columns for t >= maxlen (rows with len<maxlen got
    // zeros in-loop); harness poisons d_out so every element must be written
    for (int t = maxlen; t < T_N; ++t)
        IO<F32>::st4z(out, OUT_ALLH + ((long long)bo * T_N + t) * COLS + c0);

    IO<F32>::st4(out, OUT_SEG + (long long)bo * H_N + c0, smax);
}

extern "C" void kernel_launch(void* const* d_in, const int* in_sizes, int n_in,
                              void* d_out, int out_size, void* d_ws, size_t ws_size,
                              hipStream_t stream) {
    const void* x_seq  = d_in[0];
    const void* hidden = d_in[1];
    const void* tree   = d_in[2];
    const void* graph  = d_in[3];
    const int*  lens   = (const int*)d_in[4];
    const void* Wcs    = d_in[5];
    const void* bcs    = d_in[6];
    const void* Wz     = d_in[7];
    const void* bz     = d_in[8];
    const void* Wr     = d_in[9];
    const void* br     = d_in[10];
    const void* Wh     = d_in[11];
    const void* bh     = d_in[12];
    void* out = d_out;

    // allow >64KB dynamic LDS (once per process; host-side, capture-safe)
    static bool attr_set = false;
    if (!attr_set) {
        (void)hipFuncSetAttribute(reinterpret_cast<const void*>(&gru_kernel<true>),
                                  hipFuncAttributeMaxDynamicSharedMemorySize, SMEM_BYTES);
        (void)hipFuncSetAttribute(reinterpret_cast<const void*>(&gru_kernel<false>),
                                  hipFuncAttributeMaxDynamicSharedMemorySize, SMEM_BYTES);
        attr_set = true;
    }

    long long work = (long long)B_N * T_N * 32;
    int fill_blocks = (int)(work / 256);   // 25600

    // Launch BOTH dtype variants; each self-selects via detect_f32 and the
    // mismatching variant exits immediately. Deterministic work per call
    // => graph-capture safe.
    hipLaunchKernelGGL((latent_fill_kernel<true>),  dim3(fill_blocks), dim3(256), 0, stream,
                       tree, graph, lens, Wcs, out);
    hipLaunchKernelGGL((latent_fill_kernel<false>), dim3(fill_blocks), dim3(256), 0, stream,
                       tree, graph, lens, Wcs, out);

    hipLaunchKernelGGL((gru_kernel<true>), dim3(B_N / RB), dim3(512), SMEM_BYTES, stream,
                       x_seq, hidden, graph, lens,
                       Wcs, bcs, Wz, bz, Wr, br, Wh, bh, out);
    hipLaunchKernelGGL((gru_kernel<false>), dim3(B_N / RB), dim3(512), SMEM_BYTES, stream,
                       x_seq, hidden, graph, lens,
                       Wcs, bcs, Wz, bz, Wr, br, Wh, bh, out);
}